// Round 1
// baseline (438.007 us; speedup 1.0000x reference)
//
#include <hip/hip_runtime.h>

#define B 64
#define L 1024
#define H 768
#define NROWS (B * L)

// ---------------- Kernel 1: feats[l][b][k] = hidden[b,l,:] . w[k,:] + bias[k]
__global__ __launch_bounds__(256) void feats_kernel(
    const float* __restrict__ hidden, const float* __restrict__ w,
    const float* __restrict__ bias, float4* __restrict__ featsT)
{
    const int lane = threadIdx.x & 63;
    const int wave = (blockIdx.x * blockDim.x + threadIdx.x) >> 6;
    const int nwaves = (gridDim.x * blockDim.x) >> 6;

    // Each lane owns 12 fixed column positions: e = lane*4 + j + 256*c
    float wr[3][4][4]; // [c][j][k]
#pragma unroll
    for (int c = 0; c < 3; ++c)
#pragma unroll
        for (int j = 0; j < 4; ++j)
#pragma unroll
            for (int k = 0; k < 4; ++k)
                wr[c][j][k] = w[k * H + lane * 4 + 256 * c + j];
    const float bb0 = bias[0], bb1 = bias[1], bb2 = bias[2], bb3 = bias[3];

    for (int row = wave; row < NROWS; row += nwaves) {
        const float4* hrow = reinterpret_cast<const float4*>(hidden) + (size_t)row * (H / 4);
        float acc[4] = {0.f, 0.f, 0.f, 0.f};
#pragma unroll
        for (int c = 0; c < 3; ++c) {
            float4 h = hrow[lane + 64 * c];
            const float hv[4] = {h.x, h.y, h.z, h.w};
#pragma unroll
            for (int j = 0; j < 4; ++j)
#pragma unroll
                for (int k = 0; k < 4; ++k)
                    acc[k] = fmaf(hv[j], wr[c][j][k], acc[k]);
        }
#pragma unroll
        for (int k = 0; k < 4; ++k) {
            float v = acc[k];
#pragma unroll
            for (int s = 32; s >= 1; s >>= 1) v += __shfl_xor(v, s, 64);
            acc[k] = v;
        }
        if (lane == 0) {
            const int b = row >> 10, l = row & 1023;
            featsT[l * B + b] = make_float4(acc[0] + bb0, acc[1] + bb1, acc[2] + bb2, acc[3] + bb3);
        }
    }
}

// ---------------- Kernel 2: forward (block 0) / backward (block 1) CRF scan
__global__ __launch_bounds__(64) void scan_kernel(
    const float4* __restrict__ featsT, const int* __restrict__ seq_lens,
    const float* __restrict__ T, float4* __restrict__ alphasT,
    float4* __restrict__ betasT, float* __restrict__ logZ)
{
    const int b = threadIdx.x;
    const int sl = seq_lens[b];
    float eT[4][4];
#pragma unroll
    for (int i = 0; i < 4; ++i)
#pragma unroll
        for (int j = 0; j < 4; ++j) eT[i][j] = expf(T[i * 4 + j]);

    if (blockIdx.x == 0) {
        // ---- forward
        float4 f0 = featsT[b];
        float a0 = f0.x, a1 = f0.y, a2 = f0.z, a3 = f0.w;
        alphasT[b] = f0;

        auto fstep = [&](float4 curf, bool valid) {
            float m = fmaxf(fmaxf(a0, a1), fmaxf(a2, a3));
            float e0 = expf(a0 - m), e1 = expf(a1 - m), e2 = expf(a2 - m), e3 = expf(a3 - m);
            float s0 = (e0 * eT[0][0] + e1 * eT[1][0]) + (e2 * eT[2][0] + e3 * eT[3][0]);
            float s1 = (e0 * eT[0][1] + e1 * eT[1][1]) + (e2 * eT[2][1] + e3 * eT[3][1]);
            float s2 = (e0 * eT[0][2] + e1 * eT[1][2]) + (e2 * eT[2][2] + e3 * eT[3][2]);
            float s3 = (e0 * eT[0][3] + e1 * eT[1][3]) + (e2 * eT[2][3] + e3 * eT[3][3]);
            float n0 = curf.x + m + logf(s0);
            float n1 = curf.y + m + logf(s1);
            float n2 = curf.z + m + logf(s2);
            float n3 = curf.w + m + logf(s3);
            a0 = valid ? n0 : a0; a1 = valid ? n1 : a1;
            a2 = valid ? n2 : a2; a3 = valid ? n3 : a3;
        };

        float4 ring[8];
#pragma unroll
        for (int d = 0; d < 8; ++d) ring[d] = featsT[(1 + d) * B + b];

        int t = 1;
        for (; t + 7 <= 1023; t += 8) {
#pragma unroll
            for (int u = 0; u < 8; ++u) {
                float4 curf = ring[u];
                const int tt = t + u;
                if (tt + 8 <= 1023) ring[u] = featsT[(tt + 8) * B + b];
                fstep(curf, tt < sl);
                alphasT[tt * B + b] = make_float4(a0, a1, a2, a3);
            }
        }
#pragma unroll
        for (int u = 0; u < 7; ++u) {
            fstep(ring[u], (t + u) < sl);
            alphasT[(t + u) * B + b] = make_float4(a0, a1, a2, a3);
        }
        float m = fmaxf(fmaxf(a0, a1), fmaxf(a2, a3));
        logZ[b] = m + logf(expf(a0 - m) + expf(a1 - m) + expf(a2 - m) + expf(a3 - m));
    } else {
        // ---- backward
        float b0 = 0.f, b1 = 0.f, b2 = 0.f, b3 = 0.f;
        betasT[1023 * B + b] = make_float4(0.f, 0.f, 0.f, 0.f);

        auto bstep = [&](float4 curf, bool valid) {
            float c0 = curf.x + b0, c1 = curf.y + b1, c2 = curf.z + b2, c3 = curf.w + b3;
            float m = fmaxf(fmaxf(c0, c1), fmaxf(c2, c3));
            float e0 = expf(c0 - m), e1 = expf(c1 - m), e2 = expf(c2 - m), e3 = expf(c3 - m);
            float s0 = (e0 * eT[0][0] + e1 * eT[0][1]) + (e2 * eT[0][2] + e3 * eT[0][3]);
            float s1 = (e0 * eT[1][0] + e1 * eT[1][1]) + (e2 * eT[1][2] + e3 * eT[1][3]);
            float s2 = (e0 * eT[2][0] + e1 * eT[2][1]) + (e2 * eT[2][2] + e3 * eT[2][3]);
            float s3 = (e0 * eT[3][0] + e1 * eT[3][1]) + (e2 * eT[3][2] + e3 * eT[3][3]);
            float n0 = m + logf(s0), n1 = m + logf(s1), n2 = m + logf(s2), n3 = m + logf(s3);
            b0 = valid ? n0 : b0; b1 = valid ? n1 : b1;
            b2 = valid ? n2 : b2; b3 = valid ? n3 : b3;
        };

        float4 ring[8];
#pragma unroll
        for (int d = 0; d < 8; ++d) ring[d] = featsT[(1023 - d) * B + b];

        int n = 1023;
        for (; n - 7 >= 1; n -= 8) {
#pragma unroll
            for (int u = 0; u < 8; ++u) {
                float4 curf = ring[u];
                const int nn = n - u;
                if (nn - 8 >= 1) ring[u] = featsT[(nn - 8) * B + b];
                bstep(curf, nn < sl);
                betasT[(nn - 1) * B + b] = make_float4(b0, b1, b2, b3);
            }
        }
#pragma unroll
        for (int u = 0; u < 7; ++u) {
            const int nn = n - u; // 7..1
            bstep(ring[u], nn < sl);
            betasT[(nn - 1) * B + b] = make_float4(b0, b1, b2, b3);
        }
    }
}

// ---------------- Kernel 3: sp, s_prob, per-batch norm sums
__global__ __launch_bounds__(256) void marg_kernel(
    const float* __restrict__ alphasT, const float* __restrict__ betasT,
    const float* __restrict__ logZ, const int* __restrict__ seq_lens,
    float* __restrict__ normsum, float* __restrict__ sprob)
{
    const int b = blockIdx.x;
    const int tid = threadIdx.x;
    const float lz = logZ[b];
    const int sl = seq_lens[b];
    float v[4];
    float loc = 0.f;
#pragma unroll
    for (int c = 0; c < 4; ++c) {
        const int l = tid + 256 * c;
        const float a1 = alphasT[(l * B + b) * 4 + 1];
        const float be = betasT[(l * B + b) * 4 + 1];
        const float x = (l < sl) ? expf(a1 + be - lz) : 0.f;
        v[c] = x;
        loc += x;
    }
#pragma unroll
    for (int s = 32; s >= 1; s >>= 1) loc += __shfl_xor(loc, s, 64);
    __shared__ float red[4];
    if ((tid & 63) == 0) red[tid >> 6] = loc;
    __syncthreads();
    const float tot = red[0] + red[1] + red[2] + red[3];
    const float g = 0.5f * tot;
    const float inv = 1.0f / g;
#pragma unroll
    for (int c = 0; c < 4; ++c)
        sprob[b * L + tid + 256 * c] = v[c] * inv;
    if (tid == 0) normsum[b] = tot * inv; // == sum_l |s_prob|
}

// ---------------- Kernel 4: partial sent_vs = sum_l s_prob[b,l] * hidden[b,l,h]
__global__ __launch_bounds__(256) void sentv_kernel(
    const float* __restrict__ hidden, const float* __restrict__ sprob,
    float* __restrict__ partial)
{
    const int b = blockIdx.y;
    const int hc = blockIdx.x % 3;
    const int lc = blockIdx.x / 3;
    const int h = hc * 256 + threadIdx.x;
    const float* hb = hidden + ((size_t)b * L + (size_t)lc * 256) * H + h;
    const float* sp = sprob + b * L + lc * 256;
    float acc = 0.f;
#pragma unroll 8
    for (int l = 0; l < 256; ++l)
        acc = fmaf(sp[l], hb[(size_t)l * H], acc);
    partial[((size_t)lc * B + b) * H + h] = acc;
}

// ---------------- Kernel 5: reduce partials + norm_pen
__global__ __launch_bounds__(256) void final_kernel(
    const float* __restrict__ partial, const float* __restrict__ normsum,
    const float* __restrict__ T, float* __restrict__ out)
{
    const int idx = blockIdx.x * 256 + threadIdx.x;
    if (idx < B * H) {
        out[idx] = (partial[idx] + partial[B * H + idx]) +
                   (partial[2 * B * H + idx] + partial[3 * B * H + idx]);
    }
    if (idx == 0) {
        const float pena = fmaxf(T[4] - T[0], 0.f) + fmaxf(T[1] - T[5], 0.f);
        float s = 0.f;
        for (int b2 = 0; b2 < B; ++b2) s += normsum[b2];
        out[B * H] = 0.1f * pena + 0.1f * (s / 64.f);
    }
}

extern "C" void kernel_launch(void* const* d_in, const int* in_sizes, int n_in,
                              void* d_out, int out_size, void* d_ws, size_t ws_size,
                              hipStream_t stream) {
    const float* hidden   = (const float*)d_in[0];
    const int*   seq_lens = (const int*)d_in[4];
    const float* w        = (const float*)d_in[7];
    const float* bias     = (const float*)d_in[8];
    const float* T        = (const float*)d_in[9];

    float* ws = (float*)d_ws;
    float4* featsT  = (float4*)(ws);            // 262144 floats
    float4* alphasT = (float4*)(ws + 262144);   // 262144 floats
    float4* betasT  = (float4*)(ws + 524288);   // 262144 floats
    float*  logZ    = ws + 786432;              // 64
    float*  normsum = ws + 786496;              // 64
    float*  partial = ws + 786560;              // 4*64*768 = 196608

    float* out   = (float*)d_out;
    float* sprob = out + B * H + 1;             // s_prob region of d_out

    feats_kernel<<<2048, 256, 0, stream>>>(hidden, w, bias, featsT);
    scan_kernel<<<2, 64, 0, stream>>>(featsT, seq_lens, T, alphasT, betasT, logZ);
    marg_kernel<<<64, 256, 0, stream>>>((const float*)alphasT, (const float*)betasT,
                                        logZ, seq_lens, normsum, sprob);
    sentv_kernel<<<dim3(12, 64), 256, 0, stream>>>(hidden, sprob, partial);
    final_kernel<<<192, 256, 0, stream>>>(partial, normsum, T, out);
}

// Round 2
// 221.406 us; speedup vs baseline: 1.9783x; 1.9783x over previous
//
#include <hip/hip_runtime.h>

#define B 64
#define L 1024
#define H 768
#define NROWS (B * L)
#define LOG2E 1.4426950408889634f

#define EXP2(x) __builtin_amdgcn_exp2f(x)
#define LOG2(x) __builtin_amdgcn_logf(x)

// ---------------- Kernel 1: featsT[l][b][k] = (hidden[b,l,:].w[k,:] + bias[k]) * log2(e)
__global__ __launch_bounds__(256) void feats_kernel(
    const float* __restrict__ hidden, const float* __restrict__ w,
    const float* __restrict__ bias, float4* __restrict__ featsT)
{
    const int lane = threadIdx.x & 63;
    const int wave = (blockIdx.x * blockDim.x + threadIdx.x) >> 6;
    const int nwaves = (gridDim.x * blockDim.x) >> 6;

    float wr[3][4][4]; // [c][j][k]
#pragma unroll
    for (int c = 0; c < 3; ++c)
#pragma unroll
        for (int j = 0; j < 4; ++j)
#pragma unroll
            for (int k = 0; k < 4; ++k)
                wr[c][j][k] = w[k * H + lane * 4 + 256 * c + j];
    const float bb0 = bias[0], bb1 = bias[1], bb2 = bias[2], bb3 = bias[3];

    for (int row = wave; row < NROWS; row += nwaves) {
        const float4* hrow = reinterpret_cast<const float4*>(hidden) + (size_t)row * (H / 4);
        float acc[4] = {0.f, 0.f, 0.f, 0.f};
#pragma unroll
        for (int c = 0; c < 3; ++c) {
            float4 h = hrow[lane + 64 * c];
            const float hv[4] = {h.x, h.y, h.z, h.w};
#pragma unroll
            for (int j = 0; j < 4; ++j)
#pragma unroll
                for (int k = 0; k < 4; ++k)
                    acc[k] = fmaf(hv[j], wr[c][j][k], acc[k]);
        }
#pragma unroll
        for (int k = 0; k < 4; ++k) {
            float v = acc[k];
#pragma unroll
            for (int s = 32; s >= 1; s >>= 1) v += __shfl_xor(v, s, 64);
            acc[k] = v;
        }
        if (lane == 0) {
            const int b = row >> 10, l = row & 1023;
            featsT[l * B + b] = make_float4((acc[0] + bb0) * LOG2E, (acc[1] + bb1) * LOG2E,
                                            (acc[2] + bb2) * LOG2E, (acc[3] + bb3) * LOG2E);
        }
    }
}

// ---------------- Kernel 2: forward (block 0) / backward (block 1) CRF scan, base-2 log space
__global__ __launch_bounds__(64) void scan_kernel(
    const float4* __restrict__ featsT, const int* __restrict__ seq_lens,
    const float* __restrict__ T, float* __restrict__ alpha1,
    float* __restrict__ beta1, float* __restrict__ logZ)
{
    const int b = threadIdx.x;
    const int sl = seq_lens[b];
    // eT[i][j] = 2^(T[i][j]*log2e) = e^T[i][j]
    float eT[4][4];
#pragma unroll
    for (int i = 0; i < 4; ++i)
#pragma unroll
        for (int j = 0; j < 4; ++j) eT[i][j] = EXP2(T[i * 4 + j] * LOG2E);

    if (blockIdx.x == 0) {
        // ---- forward
        float4 f0 = featsT[b];
        float a0 = f0.x, a1 = f0.y, a2 = f0.z, a3 = f0.w;
        alpha1[b] = a1;

        auto fstep = [&](float4 curf, bool valid) {
            float m = fmaxf(fmaxf(a0, a1), fmaxf(a2, a3));
            float e0 = EXP2(a0 - m), e1 = EXP2(a1 - m), e2 = EXP2(a2 - m), e3 = EXP2(a3 - m);
            float s0 = (e0 * eT[0][0] + e1 * eT[1][0]) + (e2 * eT[2][0] + e3 * eT[3][0]);
            float s1 = (e0 * eT[0][1] + e1 * eT[1][1]) + (e2 * eT[2][1] + e3 * eT[3][1]);
            float s2 = (e0 * eT[0][2] + e1 * eT[1][2]) + (e2 * eT[2][2] + e3 * eT[3][2]);
            float s3 = (e0 * eT[0][3] + e1 * eT[1][3]) + (e2 * eT[2][3] + e3 * eT[3][3]);
            float n0 = curf.x + m + LOG2(s0);
            float n1 = curf.y + m + LOG2(s1);
            float n2 = curf.z + m + LOG2(s2);
            float n3 = curf.w + m + LOG2(s3);
            a0 = valid ? n0 : a0; a1 = valid ? n1 : a1;
            a2 = valid ? n2 : a2; a3 = valid ? n3 : a3;
        };

        float4 ring[32];
#pragma unroll
        for (int d = 0; d < 32; ++d) ring[d] = featsT[(1 + d) * B + b];

        int t = 1;
        for (; t + 31 <= 1023; t += 32) {
#pragma unroll
            for (int u = 0; u < 32; ++u) {
                float4 curf = ring[u];
                const int tt = t + u;
                if (tt + 32 <= 1023) ring[u] = featsT[(tt + 32) * B + b];
                fstep(curf, tt < sl);
                alpha1[tt * B + b] = a1;
            }
        }
#pragma unroll
        for (int u = 0; u < 31; ++u) {
            fstep(ring[u], (t + u) < sl);
            alpha1[(t + u) * B + b] = a1;
        }
        float m = fmaxf(fmaxf(a0, a1), fmaxf(a2, a3));
        logZ[b] = m + LOG2(EXP2(a0 - m) + EXP2(a1 - m) + EXP2(a2 - m) + EXP2(a3 - m));
    } else {
        // ---- backward
        float b0 = 0.f, b1 = 0.f, b2 = 0.f, b3 = 0.f;
        beta1[1023 * B + b] = 0.f;

        auto bstep = [&](float4 curf, bool valid) {
            float c0 = curf.x + b0, c1 = curf.y + b1, c2 = curf.z + b2, c3 = curf.w + b3;
            float m = fmaxf(fmaxf(c0, c1), fmaxf(c2, c3));
            float e0 = EXP2(c0 - m), e1 = EXP2(c1 - m), e2 = EXP2(c2 - m), e3 = EXP2(c3 - m);
            float s0 = (e0 * eT[0][0] + e1 * eT[0][1]) + (e2 * eT[0][2] + e3 * eT[0][3]);
            float s1 = (e0 * eT[1][0] + e1 * eT[1][1]) + (e2 * eT[1][2] + e3 * eT[1][3]);
            float s2 = (e0 * eT[2][0] + e1 * eT[2][1]) + (e2 * eT[2][2] + e3 * eT[2][3]);
            float s3 = (e0 * eT[3][0] + e1 * eT[3][1]) + (e2 * eT[3][2] + e3 * eT[3][3]);
            float n0 = m + LOG2(s0), n1 = m + LOG2(s1), n2 = m + LOG2(s2), n3 = m + LOG2(s3);
            b0 = valid ? n0 : b0; b1 = valid ? n1 : b1;
            b2 = valid ? n2 : b2; b3 = valid ? n3 : b3;
        };

        float4 ring[32];
#pragma unroll
        for (int d = 0; d < 32; ++d) ring[d] = featsT[(1023 - d) * B + b];

        int n = 1023;
        for (; n - 31 >= 1; n -= 32) {
#pragma unroll
            for (int u = 0; u < 32; ++u) {
                float4 curf = ring[u];
                const int nn = n - u;
                if (nn - 32 >= 1) ring[u] = featsT[(nn - 32) * B + b];
                bstep(curf, nn < sl);
                beta1[(nn - 1) * B + b] = b1;
            }
        }
#pragma unroll
        for (int u = 0; u < 31; ++u) {
            const int nn = n - u; // 31..1
            bstep(ring[u], nn < sl);
            beta1[(nn - 1) * B + b] = b1;
        }
    }
}

// ---------------- Kernel 3: sp, s_prob, per-batch norm sums (all base-2)
__global__ __launch_bounds__(256) void marg_kernel(
    const float* __restrict__ alpha1, const float* __restrict__ beta1,
    const float* __restrict__ logZ, const int* __restrict__ seq_lens,
    float* __restrict__ normsum, float* __restrict__ sprob)
{
    const int b = blockIdx.x;
    const int tid = threadIdx.x;
    const float lz = logZ[b];
    const int sl = seq_lens[b];
    float v[4];
    float loc = 0.f;
#pragma unroll
    for (int c = 0; c < 4; ++c) {
        const int l = tid + 256 * c;
        const float a1 = alpha1[l * B + b];
        const float be = beta1[l * B + b];
        const float x = (l < sl) ? EXP2(a1 + be - lz) : 0.f;
        v[c] = x;
        loc += x;
    }
#pragma unroll
    for (int s = 32; s >= 1; s >>= 1) loc += __shfl_xor(loc, s, 64);
    __shared__ float red[4];
    if ((tid & 63) == 0) red[tid >> 6] = loc;
    __syncthreads();
    const float tot = red[0] + red[1] + red[2] + red[3];
    const float g = 0.5f * tot;
    const float inv = 1.0f / g;
#pragma unroll
    for (int c = 0; c < 4; ++c)
        sprob[b * L + tid + 256 * c] = v[c] * inv;
    if (tid == 0) normsum[b] = tot * inv; // == sum_l |s_prob|
}

// ---------------- Kernel 4: partial sent_vs = sum_l s_prob[b,l] * hidden[b,l,h]
__global__ __launch_bounds__(256) void sentv_kernel(
    const float* __restrict__ hidden, const float* __restrict__ sprob,
    float* __restrict__ partial)
{
    const int b = blockIdx.y;
    const int hc = blockIdx.x % 3;
    const int lc = blockIdx.x / 3;
    const int h = hc * 256 + threadIdx.x;
    const float* hb = hidden + ((size_t)b * L + (size_t)lc * 256) * H + h;
    const float* sp = sprob + b * L + lc * 256;
    float acc = 0.f;
#pragma unroll 8
    for (int l = 0; l < 256; ++l)
        acc = fmaf(sp[l], hb[(size_t)l * H], acc);
    partial[((size_t)lc * B + b) * H + h] = acc;
}

// ---------------- Kernel 5: reduce partials + norm_pen
__global__ __launch_bounds__(256) void final_kernel(
    const float* __restrict__ partial, const float* __restrict__ normsum,
    const float* __restrict__ T, float* __restrict__ out)
{
    const int idx = blockIdx.x * 256 + threadIdx.x;
    if (idx < B * H) {
        out[idx] = (partial[idx] + partial[B * H + idx]) +
                   (partial[2 * B * H + idx] + partial[3 * B * H + idx]);
    }
    if (idx == 0) {
        const float pena = fmaxf(T[4] - T[0], 0.f) + fmaxf(T[1] - T[5], 0.f);
        float s = 0.f;
        for (int b2 = 0; b2 < B; ++b2) s += normsum[b2];
        out[B * H] = 0.1f * pena + 0.1f * (s / 64.f);
    }
}

extern "C" void kernel_launch(void* const* d_in, const int* in_sizes, int n_in,
                              void* d_out, int out_size, void* d_ws, size_t ws_size,
                              hipStream_t stream) {
    const float* hidden   = (const float*)d_in[0];
    const int*   seq_lens = (const int*)d_in[4];
    const float* w        = (const float*)d_in[7];
    const float* bias     = (const float*)d_in[8];
    const float* T        = (const float*)d_in[9];

    float* ws = (float*)d_ws;
    float4* featsT  = (float4*)(ws);            // 262144 floats (1 MB)
    float*  alpha1  = ws + 262144;              // 65536 floats
    float*  beta1   = ws + 327680;              // 65536 floats
    float*  logZ    = ws + 393216;              // 64
    float*  normsum = ws + 393280;              // 64
    float*  partial = ws + 393344;              // 4*64*768 = 196608

    float* out   = (float*)d_out;
    float* sprob = out + B * H + 1;             // s_prob region of d_out

    feats_kernel<<<2048, 256, 0, stream>>>(hidden, w, bias, featsT);
    scan_kernel<<<2, 64, 0, stream>>>(featsT, seq_lens, T, alpha1, beta1, logZ);
    marg_kernel<<<64, 256, 0, stream>>>(alpha1, beta1, logZ, seq_lens, normsum, sprob);
    sentv_kernel<<<dim3(12, 64), 256, 0, stream>>>(hidden, sprob, partial);
    final_kernel<<<192, 256, 0, stream>>>(partial, normsum, T, out);
}

// Round 3
// 103.790 us; speedup vs baseline: 4.2201x; 2.1332x over previous
//
#include <hip/hip_runtime.h>

#define B 64
#define L 1024
#define H 768
#define NROWS (B * L)
#define LOG2E 1.4426950408889634f
#define CS 16
#define NCH 64
#define NEG -1e30f

#define EXP2(x) __builtin_amdgcn_exp2f(x)
#define LOG2(x) __builtin_amdgcn_logf(x)

// ---------------- Kernel 1: featsT[l][b][k] = (hidden[b,l,:].w[k,:] + bias[k]) * log2(e)
__global__ __launch_bounds__(256) void feats_kernel(
    const float* __restrict__ hidden, const float* __restrict__ w,
    const float* __restrict__ bias, float4* __restrict__ featsT)
{
    const int lane = threadIdx.x & 63;
    const int wave = (blockIdx.x * blockDim.x + threadIdx.x) >> 6;
    const int nwaves = (gridDim.x * blockDim.x) >> 6;

    float wr[3][4][4];
#pragma unroll
    for (int c = 0; c < 3; ++c)
#pragma unroll
        for (int j = 0; j < 4; ++j)
#pragma unroll
            for (int k = 0; k < 4; ++k)
                wr[c][j][k] = w[k * H + lane * 4 + 256 * c + j];
    const float bb0 = bias[0], bb1 = bias[1], bb2 = bias[2], bb3 = bias[3];

    for (int row = wave; row < NROWS; row += nwaves) {
        const float4* hrow = reinterpret_cast<const float4*>(hidden) + (size_t)row * (H / 4);
        float acc[4] = {0.f, 0.f, 0.f, 0.f};
#pragma unroll
        for (int c = 0; c < 3; ++c) {
            float4 h = hrow[lane + 64 * c];
            const float hv[4] = {h.x, h.y, h.z, h.w};
#pragma unroll
            for (int j = 0; j < 4; ++j)
#pragma unroll
                for (int k = 0; k < 4; ++k)
                    acc[k] = fmaf(hv[j], wr[c][j][k], acc[k]);
        }
#pragma unroll
        for (int k = 0; k < 4; ++k) {
            float v = acc[k];
#pragma unroll
            for (int s = 32; s >= 1; s >>= 1) v += __shfl_xor(v, s, 64);
            acc[k] = v;
        }
        if (lane == 0) {
            const int b = row >> 10, l = row & 1023;
            featsT[l * B + b] = make_float4((acc[0] + bb0) * LOG2E, (acc[1] + bb1) * LOG2E,
                                            (acc[2] + bb2) * LOG2E, (acc[3] + bb3) * LOG2E);
        }
    }
}

// ---------------- Kernel 2a: per-chunk 4x4 transfer matrix (log2-semiring product)
// dir 0 (fwd): chunk c covers t in [lo,hi]; M s.t. alpha_hi = alpha_{lo-1} (row-vec) o M
// dir 1 (bwd): M s.t. beta_{lo-1} = M (col-vec) o beta_hi
__global__ __launch_bounds__(64) void chunkmat_kernel(
    const float4* __restrict__ featsT, const int* __restrict__ seq_lens,
    const float* __restrict__ T, float* __restrict__ mats)
{
    const int b = threadIdx.x;
    const int dir = blockIdx.x >= NCH;
    const int c = blockIdx.x - (dir ? NCH : 0);
    const int sl = seq_lens[b];
    const int lo = c * CS + 1;
    const int hi = min(c * CS + CS, L - 1);
    const int ns = hi - lo + 1;

    float eT2[4][4];
#pragma unroll
    for (int i = 0; i < 4; ++i)
#pragma unroll
        for (int j = 0; j < 4; ++j) eT2[i][j] = EXP2(T[i * 4 + j] * LOG2E);

    float4 fr[CS];
#pragma unroll
    for (int u = 0; u < CS; ++u) {
        const int t = dir ? max(hi - u, lo) : min(lo + u, hi);
        fr[u] = featsT[t * B + b];
    }

    float M[4][4];
#pragma unroll
    for (int i = 0; i < 4; ++i)
#pragma unroll
        for (int j = 0; j < 4; ++j) M[i][j] = (i == j) ? 0.f : NEG;

    if (dir == 0) {
#pragma unroll
        for (int u = 0; u < CS; ++u) {
            const int t = lo + u;
            const bool valid = (u < ns) && (t < sl);
            const float f[4] = {fr[u].x, fr[u].y, fr[u].z, fr[u].w};
            float nM[4][4];
#pragma unroll
            for (int i = 0; i < 4; ++i) {
                const float rm = fmaxf(fmaxf(M[i][0], M[i][1]), fmaxf(M[i][2], M[i][3]));
                const float e0 = EXP2(M[i][0] - rm), e1 = EXP2(M[i][1] - rm);
                const float e2 = EXP2(M[i][2] - rm), e3 = EXP2(M[i][3] - rm);
#pragma unroll
                for (int j = 0; j < 4; ++j) {
                    const float s = (e0 * eT2[0][j] + e1 * eT2[1][j]) + (e2 * eT2[2][j] + e3 * eT2[3][j]);
                    nM[i][j] = f[j] + rm + LOG2(s);
                }
            }
#pragma unroll
            for (int i = 0; i < 4; ++i)
#pragma unroll
                for (int j = 0; j < 4; ++j) M[i][j] = valid ? nM[i][j] : M[i][j];
        }
    } else {
#pragma unroll
        for (int u = 0; u < CS; ++u) {
            const int n = hi - u;
            const bool valid = (u < ns) && (n < sl);
            const float f[4] = {fr[u].x, fr[u].y, fr[u].z, fr[u].w};
            float nM[4][4];
#pragma unroll
            for (int j = 0; j < 4; ++j) {
                const float c0 = f[0] + M[0][j], c1 = f[1] + M[1][j];
                const float c2 = f[2] + M[2][j], c3 = f[3] + M[3][j];
                const float cm = fmaxf(fmaxf(c0, c1), fmaxf(c2, c3));
                const float g0 = EXP2(c0 - cm), g1 = EXP2(c1 - cm);
                const float g2 = EXP2(c2 - cm), g3 = EXP2(c3 - cm);
#pragma unroll
                for (int i = 0; i < 4; ++i) {
                    const float s = (g0 * eT2[i][0] + g1 * eT2[i][1]) + (g2 * eT2[i][2] + g3 * eT2[i][3]);
                    nM[i][j] = cm + LOG2(s);
                }
            }
#pragma unroll
            for (int i = 0; i < 4; ++i)
#pragma unroll
                for (int j = 0; j < 4; ++j) M[i][j] = valid ? nM[i][j] : M[i][j];
        }
    }
#pragma unroll
    for (int i = 0; i < 4; ++i)
#pragma unroll
        for (int j = 0; j < 4; ++j)
            mats[((dir * NCH + c) * 16 + i * 4 + j) * B + b] = M[i][j];
}

// ---------------- Kernel 2b: serial scan over chunk matrices -> boundary vectors, logZ
__global__ __launch_bounds__(128) void bound_kernel(
    const float4* __restrict__ featsT, const float* __restrict__ mats,
    float* __restrict__ vbound, float* __restrict__ alpha1,
    float* __restrict__ beta1, float* __restrict__ logZ)
{
    const int b = threadIdx.x & 63;
    const int dir = threadIdx.x >> 6;

    float Ms[4][16];
#pragma unroll
    for (int p = 0; p < 3; ++p) {
        const int cc = dir ? (NCH - 1 - p) : p;
#pragma unroll
        for (int k = 0; k < 16; ++k)
            Ms[p][k] = mats[((dir * NCH + cc) * 16 + k) * B + b];
    }

    float v0, v1, v2, v3;
    if (dir == 0) {
        const float4 f0 = featsT[b];
        v0 = f0.x; v1 = f0.y; v2 = f0.z; v3 = f0.w;
        alpha1[b] = v1;
    } else {
        v0 = v1 = v2 = v3 = 0.f;
        beta1[(L - 1) * B + b] = 0.f;
    }

#pragma unroll
    for (int u = 0; u < NCH; ++u) {
        const int cc = dir ? (NCH - 1 - u) : u;
        vbound[((dir * NCH + cc) * 4 + 0) * B + b] = v0;
        vbound[((dir * NCH + cc) * 4 + 1) * B + b] = v1;
        vbound[((dir * NCH + cc) * 4 + 2) * B + b] = v2;
        vbound[((dir * NCH + cc) * 4 + 3) * B + b] = v3;
        if (u + 3 < NCH) {
            const int cp = dir ? (NCH - 1 - (u + 3)) : (u + 3);
#pragma unroll
            for (int k = 0; k < 16; ++k)
                Ms[(u + 3) & 3][k] = mats[((dir * NCH + cp) * 16 + k) * B + b];
        }
        float n[4];
        if (dir == 0) {
            // row-vector: n_j = log2sum_k(v_k + M[k][j])
#pragma unroll
            for (int j = 0; j < 4; ++j) {
                const float c0 = v0 + Ms[u & 3][0 * 4 + j], c1 = v1 + Ms[u & 3][1 * 4 + j];
                const float c2 = v2 + Ms[u & 3][2 * 4 + j], c3 = v3 + Ms[u & 3][3 * 4 + j];
                const float m = fmaxf(fmaxf(c0, c1), fmaxf(c2, c3));
                const float s = (EXP2(c0 - m) + EXP2(c1 - m)) + (EXP2(c2 - m) + EXP2(c3 - m));
                n[j] = m + LOG2(s);
            }
        } else {
            // col-vector: n_i = log2sum_j(M[i][j] + v_j)
#pragma unroll
            for (int i = 0; i < 4; ++i) {
                const float c0 = v0 + Ms[u & 3][i * 4 + 0], c1 = v1 + Ms[u & 3][i * 4 + 1];
                const float c2 = v2 + Ms[u & 3][i * 4 + 2], c3 = v3 + Ms[u & 3][i * 4 + 3];
                const float m = fmaxf(fmaxf(c0, c1), fmaxf(c2, c3));
                const float s = (EXP2(c0 - m) + EXP2(c1 - m)) + (EXP2(c2 - m) + EXP2(c3 - m));
                n[i] = m + LOG2(s);
            }
        }
        v0 = n[0]; v1 = n[1]; v2 = n[2]; v3 = n[3];
    }
    if (dir == 0) {
        const float m = fmaxf(fmaxf(v0, v1), fmaxf(v2, v3));
        logZ[b] = m + LOG2(EXP2(v0 - m) + EXP2(v1 - m) + EXP2(v2 - m) + EXP2(v3 - m));
    }
}

// ---------------- Kernel 2c: replay each chunk from its boundary vector, write alpha1/beta1
__global__ __launch_bounds__(64) void rescan_kernel(
    const float4* __restrict__ featsT, const int* __restrict__ seq_lens,
    const float* __restrict__ T, const float* __restrict__ vbound,
    float* __restrict__ alpha1, float* __restrict__ beta1)
{
    const int b = threadIdx.x;
    const int dir = blockIdx.x >= NCH;
    const int c = blockIdx.x - (dir ? NCH : 0);
    const int sl = seq_lens[b];
    const int lo = c * CS + 1;
    const int hi = min(c * CS + CS, L - 1);
    const int ns = hi - lo + 1;

    float eT2[4][4];
#pragma unroll
    for (int i = 0; i < 4; ++i)
#pragma unroll
        for (int j = 0; j < 4; ++j) eT2[i][j] = EXP2(T[i * 4 + j] * LOG2E);

    float4 fr[CS];
#pragma unroll
    for (int u = 0; u < CS; ++u) {
        const int t = dir ? max(hi - u, lo) : min(lo + u, hi);
        fr[u] = featsT[t * B + b];
    }

    float v0 = vbound[((dir * NCH + c) * 4 + 0) * B + b];
    float v1 = vbound[((dir * NCH + c) * 4 + 1) * B + b];
    float v2 = vbound[((dir * NCH + c) * 4 + 2) * B + b];
    float v3 = vbound[((dir * NCH + c) * 4 + 3) * B + b];

    if (dir == 0) {
#pragma unroll
        for (int u = 0; u < CS; ++u) {
            if (u < ns) {
                const int t = lo + u;
                const bool valid = t < sl;
                const float4 f = fr[u];
                const float m = fmaxf(fmaxf(v0, v1), fmaxf(v2, v3));
                const float e0 = EXP2(v0 - m), e1 = EXP2(v1 - m), e2 = EXP2(v2 - m), e3 = EXP2(v3 - m);
                const float s0 = (e0 * eT2[0][0] + e1 * eT2[1][0]) + (e2 * eT2[2][0] + e3 * eT2[3][0]);
                const float s1 = (e0 * eT2[0][1] + e1 * eT2[1][1]) + (e2 * eT2[2][1] + e3 * eT2[3][1]);
                const float s2 = (e0 * eT2[0][2] + e1 * eT2[1][2]) + (e2 * eT2[2][2] + e3 * eT2[3][2]);
                const float s3 = (e0 * eT2[0][3] + e1 * eT2[1][3]) + (e2 * eT2[2][3] + e3 * eT2[3][3]);
                const float n0 = f.x + m + LOG2(s0), n1 = f.y + m + LOG2(s1);
                const float n2 = f.z + m + LOG2(s2), n3 = f.w + m + LOG2(s3);
                v0 = valid ? n0 : v0; v1 = valid ? n1 : v1;
                v2 = valid ? n2 : v2; v3 = valid ? n3 : v3;
                alpha1[t * B + b] = v1;
            }
        }
    } else {
#pragma unroll
        for (int u = 0; u < CS; ++u) {
            if (u < ns) {
                const int n = hi - u;
                const bool valid = n < sl;
                const float4 f = fr[u];
                const float c0 = f.x + v0, c1 = f.y + v1, c2 = f.z + v2, c3 = f.w + v3;
                const float m = fmaxf(fmaxf(c0, c1), fmaxf(c2, c3));
                const float g0 = EXP2(c0 - m), g1 = EXP2(c1 - m), g2 = EXP2(c2 - m), g3 = EXP2(c3 - m);
                const float s0 = (g0 * eT2[0][0] + g1 * eT2[0][1]) + (g2 * eT2[0][2] + g3 * eT2[0][3]);
                const float s1 = (g0 * eT2[1][0] + g1 * eT2[1][1]) + (g2 * eT2[1][2] + g3 * eT2[1][3]);
                const float s2 = (g0 * eT2[2][0] + g1 * eT2[2][1]) + (g2 * eT2[2][2] + g3 * eT2[2][3]);
                const float s3 = (g0 * eT2[3][0] + g1 * eT2[3][1]) + (g2 * eT2[3][2] + g3 * eT2[3][3]);
                const float n0 = m + LOG2(s0), n1 = m + LOG2(s1);
                const float n2 = m + LOG2(s2), n3 = m + LOG2(s3);
                v0 = valid ? n0 : v0; v1 = valid ? n1 : v1;
                v2 = valid ? n2 : v2; v3 = valid ? n3 : v3;
                beta1[(n - 1) * B + b] = v1;
            }
        }
    }
}

// ---------------- Kernel 3: sp, s_prob, per-batch norm sums (all base-2)
__global__ __launch_bounds__(256) void marg_kernel(
    const float* __restrict__ alpha1, const float* __restrict__ beta1,
    const float* __restrict__ logZ, const int* __restrict__ seq_lens,
    float* __restrict__ normsum, float* __restrict__ sprob)
{
    const int b = blockIdx.x;
    const int tid = threadIdx.x;
    const float lz = logZ[b];
    const int sl = seq_lens[b];
    float v[4];
    float loc = 0.f;
#pragma unroll
    for (int c = 0; c < 4; ++c) {
        const int l = tid + 256 * c;
        const float a1 = alpha1[l * B + b];
        const float be = beta1[l * B + b];
        const float x = (l < sl) ? EXP2(a1 + be - lz) : 0.f;
        v[c] = x;
        loc += x;
    }
#pragma unroll
    for (int s = 32; s >= 1; s >>= 1) loc += __shfl_xor(loc, s, 64);
    __shared__ float red[4];
    if ((tid & 63) == 0) red[tid >> 6] = loc;
    __syncthreads();
    const float tot = red[0] + red[1] + red[2] + red[3];
    const float g = 0.5f * tot;
    const float inv = 1.0f / g;
#pragma unroll
    for (int c = 0; c < 4; ++c)
        sprob[b * L + tid + 256 * c] = v[c] * inv;
    if (tid == 0) normsum[b] = tot * inv;
}

// ---------------- Kernel 4: partial sent_vs = sum_l s_prob[b,l] * hidden[b,l,h]
__global__ __launch_bounds__(256) void sentv_kernel(
    const float* __restrict__ hidden, const float* __restrict__ sprob,
    float* __restrict__ partial)
{
    const int b = blockIdx.y;
    const int hc = blockIdx.x % 3;
    const int lc = blockIdx.x / 3;
    const int h = hc * 256 + threadIdx.x;
    const float* hb = hidden + ((size_t)b * L + (size_t)lc * 256) * H + h;
    const float* sp = sprob + b * L + lc * 256;
    float acc = 0.f;
#pragma unroll 8
    for (int l = 0; l < 256; ++l)
        acc = fmaf(sp[l], hb[(size_t)l * H], acc);
    partial[((size_t)lc * B + b) * H + h] = acc;
}

// ---------------- Kernel 5: reduce partials + norm_pen
__global__ __launch_bounds__(256) void final_kernel(
    const float* __restrict__ partial, const float* __restrict__ normsum,
    const float* __restrict__ T, float* __restrict__ out)
{
    const int idx = blockIdx.x * 256 + threadIdx.x;
    if (idx < B * H) {
        out[idx] = (partial[idx] + partial[B * H + idx]) +
                   (partial[2 * B * H + idx] + partial[3 * B * H + idx]);
    }
    if (idx == 0) {
        const float pena = fmaxf(T[4] - T[0], 0.f) + fmaxf(T[1] - T[5], 0.f);
        float s = 0.f;
        for (int b2 = 0; b2 < B; ++b2) s += normsum[b2];
        out[B * H] = 0.1f * pena + 0.1f * (s / 64.f);
    }
}

extern "C" void kernel_launch(void* const* d_in, const int* in_sizes, int n_in,
                              void* d_out, int out_size, void* d_ws, size_t ws_size,
                              hipStream_t stream) {
    const float* hidden   = (const float*)d_in[0];
    const int*   seq_lens = (const int*)d_in[4];
    const float* w        = (const float*)d_in[7];
    const float* bias     = (const float*)d_in[8];
    const float* T        = (const float*)d_in[9];

    float* ws = (float*)d_ws;
    float4* featsT  = (float4*)(ws);            // 262144 floats
    float*  alpha1  = ws + 262144;              // 65536
    float*  beta1   = ws + 327680;              // 65536
    float*  logZ    = ws + 393216;              // 64
    float*  normsum = ws + 393280;              // 64
    float*  partial = ws + 393344;              // 196608
    float*  mats    = ws + 589952;              // 2*64*16*64 = 131072
    float*  vbound  = ws + 721024;              // 2*64*4*64 = 32768

    float* out   = (float*)d_out;
    float* sprob = out + B * H + 1;

    feats_kernel<<<2048, 256, 0, stream>>>(hidden, w, bias, featsT);
    chunkmat_kernel<<<2 * NCH, 64, 0, stream>>>(featsT, seq_lens, T, mats);
    bound_kernel<<<1, 128, 0, stream>>>(featsT, mats, vbound, alpha1, beta1, logZ);
    rescan_kernel<<<2 * NCH, 64, 0, stream>>>(featsT, seq_lens, T, vbound, alpha1, beta1);
    marg_kernel<<<64, 256, 0, stream>>>(alpha1, beta1, logZ, seq_lens, normsum, sprob);
    sentv_kernel<<<dim3(12, 64), 256, 0, stream>>>(hidden, sprob, partial);
    final_kernel<<<192, 256, 0, stream>>>(partial, normsum, T, out);
}

// Round 4
// 103.458 us; speedup vs baseline: 4.2337x; 1.0032x over previous
//
#include <hip/hip_runtime.h>

#define B 64
#define L 1024
#define H 768
#define NROWS (B * L)
#define LOG2E 1.4426950408889634f
#define CS 16
#define NCH 64
#define NEG -1e30f

#define EXP2(x) __builtin_amdgcn_exp2f(x)
#define LOG2(x) __builtin_amdgcn_logf(x)

// ---------------- Kernel 1: featsT[l][b][k] = (hidden[b,l,:].w[k,:] + bias[k]) * log2(e)
__global__ __launch_bounds__(256) void feats_kernel(
    const float* __restrict__ hidden, const float* __restrict__ w,
    const float* __restrict__ bias, float4* __restrict__ featsT)
{
    const int lane = threadIdx.x & 63;
    const int wave = (blockIdx.x * blockDim.x + threadIdx.x) >> 6;
    const int nwaves = (gridDim.x * blockDim.x) >> 6;

    float wr[3][4][4];
#pragma unroll
    for (int c = 0; c < 3; ++c)
#pragma unroll
        for (int j = 0; j < 4; ++j)
#pragma unroll
            for (int k = 0; k < 4; ++k)
                wr[c][j][k] = w[k * H + lane * 4 + 256 * c + j];
    const float bb0 = bias[0], bb1 = bias[1], bb2 = bias[2], bb3 = bias[3];

    for (int row = wave; row < NROWS; row += nwaves) {
        const float4* hrow = reinterpret_cast<const float4*>(hidden) + (size_t)row * (H / 4);
        float acc[4] = {0.f, 0.f, 0.f, 0.f};
#pragma unroll
        for (int c = 0; c < 3; ++c) {
            float4 h = hrow[lane + 64 * c];
            const float hv[4] = {h.x, h.y, h.z, h.w};
#pragma unroll
            for (int j = 0; j < 4; ++j)
#pragma unroll
                for (int k = 0; k < 4; ++k)
                    acc[k] = fmaf(hv[j], wr[c][j][k], acc[k]);
        }
#pragma unroll
        for (int k = 0; k < 4; ++k) {
            float v = acc[k];
#pragma unroll
            for (int s = 32; s >= 1; s >>= 1) v += __shfl_xor(v, s, 64);
            acc[k] = v;
        }
        if (lane == 0) {
            const int b = row >> 10, l = row & 1023;
            featsT[l * B + b] = make_float4((acc[0] + bb0) * LOG2E, (acc[1] + bb1) * LOG2E,
                                            (acc[2] + bb2) * LOG2E, (acc[3] + bb3) * LOG2E);
        }
    }
}

// ---------------- Kernel 2a: per-chunk 4x4 transfer matrices, both dirs (wave0 fwd / wave1 bwd)
__global__ __launch_bounds__(128) void chunkmat_kernel(
    const float4* __restrict__ featsT, const int* __restrict__ seq_lens,
    const float* __restrict__ T, float* __restrict__ mats)
{
    const int b = threadIdx.x & 63;
    const int dir = threadIdx.x >> 6;
    const int c = blockIdx.x;
    const int sl = seq_lens[b];
    const int lo = c * CS + 1;
    const int hi = min(c * CS + CS, L - 1);
    const int ns = hi - lo + 1;

    float eT2[4][4];
#pragma unroll
    for (int i = 0; i < 4; ++i)
#pragma unroll
        for (int j = 0; j < 4; ++j) eT2[i][j] = EXP2(T[i * 4 + j] * LOG2E);

    float4 fr[CS];
#pragma unroll
    for (int u = 0; u < CS; ++u) {
        const int t = dir ? max(hi - u, lo) : min(lo + u, hi);
        fr[u] = featsT[t * B + b];
    }

    float M[4][4];
#pragma unroll
    for (int i = 0; i < 4; ++i)
#pragma unroll
        for (int j = 0; j < 4; ++j) M[i][j] = (i == j) ? 0.f : NEG;

    if (dir == 0) {
#pragma unroll
        for (int u = 0; u < CS; ++u) {
            const int t = lo + u;
            const bool valid = (u < ns) && (t < sl);
            const float f[4] = {fr[u].x, fr[u].y, fr[u].z, fr[u].w};
            float nM[4][4];
#pragma unroll
            for (int i = 0; i < 4; ++i) {
                const float rm = fmaxf(fmaxf(M[i][0], M[i][1]), fmaxf(M[i][2], M[i][3]));
                const float e0 = EXP2(M[i][0] - rm), e1 = EXP2(M[i][1] - rm);
                const float e2 = EXP2(M[i][2] - rm), e3 = EXP2(M[i][3] - rm);
#pragma unroll
                for (int j = 0; j < 4; ++j) {
                    const float s = (e0 * eT2[0][j] + e1 * eT2[1][j]) + (e2 * eT2[2][j] + e3 * eT2[3][j]);
                    nM[i][j] = f[j] + rm + LOG2(s);
                }
            }
#pragma unroll
            for (int i = 0; i < 4; ++i)
#pragma unroll
                for (int j = 0; j < 4; ++j) M[i][j] = valid ? nM[i][j] : M[i][j];
        }
    } else {
#pragma unroll
        for (int u = 0; u < CS; ++u) {
            const int n = hi - u;
            const bool valid = (u < ns) && (n < sl);
            const float f[4] = {fr[u].x, fr[u].y, fr[u].z, fr[u].w};
            float nM[4][4];
#pragma unroll
            for (int j = 0; j < 4; ++j) {
                const float c0 = f[0] + M[0][j], c1 = f[1] + M[1][j];
                const float c2 = f[2] + M[2][j], c3 = f[3] + M[3][j];
                const float cm = fmaxf(fmaxf(c0, c1), fmaxf(c2, c3));
                const float g0 = EXP2(c0 - cm), g1 = EXP2(c1 - cm);
                const float g2 = EXP2(c2 - cm), g3 = EXP2(c3 - cm);
#pragma unroll
                for (int i = 0; i < 4; ++i) {
                    const float s = (g0 * eT2[i][0] + g1 * eT2[i][1]) + (g2 * eT2[i][2] + g3 * eT2[i][3]);
                    nM[i][j] = cm + LOG2(s);
                }
            }
#pragma unroll
            for (int i = 0; i < 4; ++i)
#pragma unroll
                for (int j = 0; j < 4; ++j) M[i][j] = valid ? nM[i][j] : M[i][j];
        }
    }
#pragma unroll
    for (int i = 0; i < 4; ++i)
#pragma unroll
        for (int j = 0; j < 4; ++j)
            mats[((dir * NCH + c) * 16 + i * 4 + j) * B + b] = M[i][j];
}

// ---------------- Kernel 2b: serial scan over chunk matrices -> boundary vectors, logZ
__global__ __launch_bounds__(128) void bound_kernel(
    const float4* __restrict__ featsT, const float* __restrict__ mats,
    float* __restrict__ vbound, float* __restrict__ logZ)
{
    const int b = threadIdx.x & 63;
    const int dir = threadIdx.x >> 6;

    float Ms[4][16];
#pragma unroll
    for (int p = 0; p < 3; ++p) {
        const int cc = dir ? (NCH - 1 - p) : p;
#pragma unroll
        for (int k = 0; k < 16; ++k)
            Ms[p][k] = mats[((dir * NCH + cc) * 16 + k) * B + b];
    }

    float v0, v1, v2, v3;
    if (dir == 0) {
        const float4 f0 = featsT[b];
        v0 = f0.x; v1 = f0.y; v2 = f0.z; v3 = f0.w;
    } else {
        v0 = v1 = v2 = v3 = 0.f;
    }

#pragma unroll
    for (int u = 0; u < NCH; ++u) {
        const int cc = dir ? (NCH - 1 - u) : u;
        vbound[((dir * NCH + cc) * 4 + 0) * B + b] = v0;
        vbound[((dir * NCH + cc) * 4 + 1) * B + b] = v1;
        vbound[((dir * NCH + cc) * 4 + 2) * B + b] = v2;
        vbound[((dir * NCH + cc) * 4 + 3) * B + b] = v3;
        if (u + 3 < NCH) {
            const int cp = dir ? (NCH - 1 - (u + 3)) : (u + 3);
#pragma unroll
            for (int k = 0; k < 16; ++k)
                Ms[(u + 3) & 3][k] = mats[((dir * NCH + cp) * 16 + k) * B + b];
        }
        float n[4];
        if (dir == 0) {
#pragma unroll
            for (int j = 0; j < 4; ++j) {
                const float c0 = v0 + Ms[u & 3][0 * 4 + j], c1 = v1 + Ms[u & 3][1 * 4 + j];
                const float c2 = v2 + Ms[u & 3][2 * 4 + j], c3 = v3 + Ms[u & 3][3 * 4 + j];
                const float m = fmaxf(fmaxf(c0, c1), fmaxf(c2, c3));
                const float s = (EXP2(c0 - m) + EXP2(c1 - m)) + (EXP2(c2 - m) + EXP2(c3 - m));
                n[j] = m + LOG2(s);
            }
        } else {
#pragma unroll
            for (int i = 0; i < 4; ++i) {
                const float c0 = v0 + Ms[u & 3][i * 4 + 0], c1 = v1 + Ms[u & 3][i * 4 + 1];
                const float c2 = v2 + Ms[u & 3][i * 4 + 2], c3 = v3 + Ms[u & 3][i * 4 + 3];
                const float m = fmaxf(fmaxf(c0, c1), fmaxf(c2, c3));
                const float s = (EXP2(c0 - m) + EXP2(c1 - m)) + (EXP2(c2 - m) + EXP2(c3 - m));
                n[i] = m + LOG2(s);
            }
        }
        v0 = n[0]; v1 = n[1]; v2 = n[2]; v3 = n[3];
    }
    if (dir == 0) {
        const float m = fmaxf(fmaxf(v0, v1), fmaxf(v2, v3));
        logZ[b] = m + LOG2(EXP2(v0 - m) + EXP2(v1 - m) + EXP2(v2 - m) + EXP2(v3 - m));
    }
}

// ---------------- Kernel 2c (fused rescan+marg): block c owns positions [16c..16c+15];
// wave0 computes alpha1 there, wave1 computes beta1 there; sp_unnorm + per-chunk sums out.
__global__ __launch_bounds__(128) void rescan_sp_kernel(
    const float4* __restrict__ featsT, const int* __restrict__ seq_lens,
    const float* __restrict__ T, const float* __restrict__ vbound,
    const float* __restrict__ logZ, float* __restrict__ spu,
    float* __restrict__ chunksum)
{
    const int tid = threadIdx.x;
    const int b = tid & 63;
    const int dir = tid >> 6;
    const int c = blockIdx.x;
    const int sl = seq_lens[b];
    const int base = c * CS;

    float eT2[4][4];
#pragma unroll
    for (int i = 0; i < 4; ++i)
#pragma unroll
        for (int j = 0; j < 4; ++j) eT2[i][j] = EXP2(T[i * 4 + j] * LOG2E);

    __shared__ float ldb[CS * 64];

    if (dir == 1) {
        // beta over positions [base .. base+15]
        float v0 = vbound[((NCH + c) * 4 + 0) * B + b];
        float v1 = vbound[((NCH + c) * 4 + 1) * B + b];
        float v2 = vbound[((NCH + c) * 4 + 2) * B + b];
        float v3 = vbound[((NCH + c) * 4 + 3) * B + b];
        const bool last = (c == NCH - 1);
        const int hi_n = last ? (L - 1) : (base + CS); // first n to process
        const int cnt = last ? (CS - 1) : CS;
        if (last) ldb[15 * 64 + b] = v1; // beta_{1023} = 0 (the loaded vbound)
        float4 fr[CS];
#pragma unroll
        for (int u = 0; u < CS; ++u) fr[u] = featsT[max(hi_n - u, base + 1) * B + b];
#pragma unroll
        for (int u = 0; u < CS; ++u) {
            if (u < cnt) {
                const int n = hi_n - u;
                const bool valid = n < sl;
                const float4 f = fr[u];
                const float c0 = f.x + v0, c1 = f.y + v1, c2 = f.z + v2, c3 = f.w + v3;
                const float m = fmaxf(fmaxf(c0, c1), fmaxf(c2, c3));
                const float g0 = EXP2(c0 - m), g1 = EXP2(c1 - m), g2 = EXP2(c2 - m), g3 = EXP2(c3 - m);
                const float s0 = (g0 * eT2[0][0] + g1 * eT2[0][1]) + (g2 * eT2[0][2] + g3 * eT2[0][3]);
                const float s1 = (g0 * eT2[1][0] + g1 * eT2[1][1]) + (g2 * eT2[1][2] + g3 * eT2[1][3]);
                const float s2 = (g0 * eT2[2][0] + g1 * eT2[2][1]) + (g2 * eT2[2][2] + g3 * eT2[2][3]);
                const float s3 = (g0 * eT2[3][0] + g1 * eT2[3][1]) + (g2 * eT2[3][2] + g3 * eT2[3][3]);
                const float n0 = m + LOG2(s0), n1 = m + LOG2(s1);
                const float n2 = m + LOG2(s2), n3 = m + LOG2(s3);
                v0 = valid ? n0 : v0; v1 = valid ? n1 : v1;
                v2 = valid ? n2 : v2; v3 = valid ? n3 : v3;
                ldb[(n - 1 - base) * 64 + b] = v1;
            }
        }
    }

    float av[CS];
    if (dir == 0) {
        // alpha over positions [base .. base+15]
        float a0 = vbound[(c * 4 + 0) * B + b];
        float a1 = vbound[(c * 4 + 1) * B + b];
        float a2 = vbound[(c * 4 + 2) * B + b];
        float a3 = vbound[(c * 4 + 3) * B + b];
        av[0] = a1;
        float4 fr[CS - 1];
#pragma unroll
        for (int u = 1; u < CS; ++u) fr[u - 1] = featsT[(base + u) * B + b];
#pragma unroll
        for (int u = 1; u < CS; ++u) {
            const int t = base + u;
            const bool valid = t < sl;
            const float4 f = fr[u - 1];
            const float m = fmaxf(fmaxf(a0, a1), fmaxf(a2, a3));
            const float e0 = EXP2(a0 - m), e1 = EXP2(a1 - m), e2 = EXP2(a2 - m), e3 = EXP2(a3 - m);
            const float s0 = (e0 * eT2[0][0] + e1 * eT2[1][0]) + (e2 * eT2[2][0] + e3 * eT2[3][0]);
            const float s1 = (e0 * eT2[0][1] + e1 * eT2[1][1]) + (e2 * eT2[2][1] + e3 * eT2[3][1]);
            const float s2 = (e0 * eT2[0][2] + e1 * eT2[1][2]) + (e2 * eT2[2][2] + e3 * eT2[3][2]);
            const float s3 = (e0 * eT2[0][3] + e1 * eT2[1][3]) + (e2 * eT2[2][3] + e3 * eT2[3][3]);
            const float n0 = f.x + m + LOG2(s0), n1 = f.y + m + LOG2(s1);
            const float n2 = f.z + m + LOG2(s2), n3 = f.w + m + LOG2(s3);
            a0 = valid ? n0 : a0; a1 = valid ? n1 : a1;
            a2 = valid ? n2 : a2; a3 = valid ? n3 : a3;
            av[u] = a1;
        }
    }

    __syncthreads();

    if (dir == 0) {
        const float lz = logZ[b];
        float sp[CS];
        float local = 0.f;
#pragma unroll
        for (int u = 0; u < CS; ++u) {
            const int l = base + u;
            const float x = (l < sl) ? EXP2(av[u] + ldb[u * 64 + b] - lz) : 0.f;
            sp[u] = x;
            local += x;
        }
        float4* dst = reinterpret_cast<float4*>(spu + b * L + base);
#pragma unroll
        for (int q = 0; q < 4; ++q)
            dst[q] = make_float4(sp[4 * q], sp[4 * q + 1], sp[4 * q + 2], sp[4 * q + 3]);
        chunksum[c * 64 + b] = local;
    }
}

// ---------------- Kernel 4: sent_vs partials (float4 per thread, /gamma folded in)
__global__ __launch_bounds__(192) void sentv_kernel(
    const float* __restrict__ hidden, const float* __restrict__ spu,
    const float* __restrict__ chunksum, float* __restrict__ partial)
{
    const int lc = blockIdx.x;
    const int b = blockIdx.y;
    const int tid = threadIdx.x;

    __shared__ float s_inv;
    if (tid < 64) {
        float v = chunksum[tid * 64 + b];
#pragma unroll
        for (int s = 32; s >= 1; s >>= 1) v += __shfl_xor(v, s, 64);
        if (tid == 0) s_inv = 2.0f / v; // 1/gamma
    }
    __syncthreads();
    const float inv = s_inv;

    const float4* hb = reinterpret_cast<const float4*>(hidden + ((size_t)b * L + lc * 256) * H) + tid;
    const float* sp = spu + b * L + lc * 256;

    float4 acc = make_float4(0.f, 0.f, 0.f, 0.f);
#pragma unroll 4
    for (int l0 = 0; l0 < 256; l0 += 4) {
        const float4 s4 = *reinterpret_cast<const float4*>(sp + l0);
        const float4 h0 = hb[(size_t)(l0 + 0) * 192];
        const float4 h1 = hb[(size_t)(l0 + 1) * 192];
        const float4 h2 = hb[(size_t)(l0 + 2) * 192];
        const float4 h3 = hb[(size_t)(l0 + 3) * 192];
        acc.x = fmaf(s4.x, h0.x, acc.x); acc.y = fmaf(s4.x, h0.y, acc.y);
        acc.z = fmaf(s4.x, h0.z, acc.z); acc.w = fmaf(s4.x, h0.w, acc.w);
        acc.x = fmaf(s4.y, h1.x, acc.x); acc.y = fmaf(s4.y, h1.y, acc.y);
        acc.z = fmaf(s4.y, h1.z, acc.z); acc.w = fmaf(s4.y, h1.w, acc.w);
        acc.x = fmaf(s4.z, h2.x, acc.x); acc.y = fmaf(s4.z, h2.y, acc.y);
        acc.z = fmaf(s4.z, h2.z, acc.z); acc.w = fmaf(s4.z, h2.w, acc.w);
        acc.x = fmaf(s4.w, h3.x, acc.x); acc.y = fmaf(s4.w, h3.y, acc.y);
        acc.z = fmaf(s4.w, h3.z, acc.z); acc.w = fmaf(s4.w, h3.w, acc.w);
    }
    acc.x *= inv; acc.y *= inv; acc.z *= inv; acc.w *= inv;
    reinterpret_cast<float4*>(partial)[((size_t)lc * B + b) * 192 + tid] = acc;
}

// ---------------- Kernel 4b: normalize sprob output + normsum (off alpha-path)
__global__ __launch_bounds__(256) void normalize_kernel(
    const float* __restrict__ spu, const float* __restrict__ chunksum,
    float* __restrict__ sprob, float* __restrict__ normsum)
{
    const int b = blockIdx.x;
    const int tid = threadIdx.x;
    __shared__ float s_tot;
    if (tid < 64) {
        float v = chunksum[tid * 64 + b];
#pragma unroll
        for (int s = 32; s >= 1; s >>= 1) v += __shfl_xor(v, s, 64);
        if (tid == 0) s_tot = v;
    }
    __syncthreads();
    const float tot = s_tot;
    const float inv = 1.0f / (0.5f * tot);
    const float4 v4 = reinterpret_cast<const float4*>(spu + b * L)[tid];
    reinterpret_cast<float4*>(sprob + b * L)[tid] =
        make_float4(v4.x * inv, v4.y * inv, v4.z * inv, v4.w * inv);
    if (tid == 0) normsum[b] = tot * inv;
}

// ---------------- Kernel 5: reduce partials + norm_pen
__global__ __launch_bounds__(256) void final_kernel(
    const float* __restrict__ partial, const float* __restrict__ normsum,
    const float* __restrict__ T, float* __restrict__ out)
{
    const int idx = blockIdx.x * 256 + threadIdx.x;
    if (idx < B * H) {
        out[idx] = (partial[idx] + partial[B * H + idx]) +
                   (partial[2 * B * H + idx] + partial[3 * B * H + idx]);
    }
    if (idx == 0) {
        const float pena = fmaxf(T[4] - T[0], 0.f) + fmaxf(T[1] - T[5], 0.f);
        float s = 0.f;
        for (int b2 = 0; b2 < B; ++b2) s += normsum[b2];
        out[B * H] = 0.1f * pena + 0.1f * (s / 64.f);
    }
}

extern "C" void kernel_launch(void* const* d_in, const int* in_sizes, int n_in,
                              void* d_out, int out_size, void* d_ws, size_t ws_size,
                              hipStream_t stream) {
    const float* hidden   = (const float*)d_in[0];
    const int*   seq_lens = (const int*)d_in[4];
    const float* w        = (const float*)d_in[7];
    const float* bias     = (const float*)d_in[8];
    const float* T        = (const float*)d_in[9];

    float* ws = (float*)d_ws;
    float4* featsT   = (float4*)(ws);           // 262144 floats
    float*  mats     = ws + 262144;             // 131072
    float*  vbound   = ws + 393216;             // 32768
    float*  logZ     = ws + 425984;             // 64
    float*  chunksum = ws + 426048;             // 4096
    float*  spu      = ws + 430144;             // 65536
    float*  partial  = ws + 495680;             // 196608
    float*  normsum  = ws + 692288;             // 64

    float* out   = (float*)d_out;
    float* sprob = out + B * H + 1;

    feats_kernel<<<2048, 256, 0, stream>>>(hidden, w, bias, featsT);
    chunkmat_kernel<<<NCH, 128, 0, stream>>>(featsT, seq_lens, T, mats);
    bound_kernel<<<1, 128, 0, stream>>>(featsT, mats, vbound, logZ);
    rescan_sp_kernel<<<NCH, 128, 0, stream>>>(featsT, seq_lens, T, vbound, logZ, spu, chunksum);
    sentv_kernel<<<dim3(4, 64), 192, 0, stream>>>(hidden, spu, chunksum, partial);
    normalize_kernel<<<64, 256, 0, stream>>>(spu, chunksum, sprob, normsum);
    final_kernel<<<192, 256, 0, stream>>>(partial, normsum, T, out);
}